// Round 4
// baseline (599.392 us; speedup 1.0000x reference)
//
#include <hip/hip_runtime.h>

// AttDownsample: x [32,768,56,56] f32 -> y [32,768,28,28] f32
// v4: FULL FUSION into one kernel, zero workspace.
// Block = (n, ho). Phase 1: 48 sub-chunks of 16 ch through double-buffered LDS tile,
// scores accumulated in registers over all 768 ch (no atomics/ws/memset). In-block
// softmax (252 vals). Phase 2: re-loop sub-chunks (L3-hot re-read) and write out.

constexpr int N_  = 32;
constexpr int C_  = 768;
constexpr int H_  = 56;
constexpr int W_  = 56;
constexpr int HO_ = 28;
constexpr int WO_ = 28;

constexpr int SC   = 16;              // channels per sub-chunk
constexpr int NSUB = C_ / SC;         // 48
constexpr int TW   = 58;              // data cols 0..55; 56,57 stay zero (ghost)
constexpr int TILE = SC * 3 * TW;     // 2784 floats
constexpr int HW_  = H_ * W_;         // 3136

__global__ __launch_bounds__(256)
void fused_kernel(const float* __restrict__ x, float* __restrict__ out) {
    // two front-padded tile buffers (pad slot serves col -1 of row 0), + reduce + attn
    __shared__ float raw[4 + TILE + 4 + TILE];   // 22304 B
    __shared__ float sred[8 * 252];              // 8064 B  [g][wo*9+k]
    __shared__ float attn_s[252];                // 1008 B  [wo][k]
    float* bufA = raw + 4;
    float* bufB = raw + 4 + TILE + 4;

    const int tid  = threadIdx.x;
    const int blk  = blockIdx.x;
    const int n    = blk / HO_;                  // consecutive blocks share n, adjacent ho
    const int ho   = blk - n * HO_;
    const int row0 = 2 * ho - 1;                 // input row of tile row r=0 (only ho=0 OOB)

    // zero everything once; ghost cols / front pads / (ho==0) row 0 stay zero forever
    for (int i = tid; i < 2 * TILE + 8; i += 256) raw[i] = 0.f;

    const float* xb = x + (size_t)n * C_ * HW_;

    auto stage = [&](float* tb, int sub) {
        const float* xs = xb + (size_t)(sub * SC) * HW_;
        // 16 ch x 3 rows x 14 float4 = 672 vector loads, ~2.6 per thread
        for (int i = tid; i < SC * 3 * 14; i += 256) {
            int c    = i / 42;
            int rem  = i - c * 42;
            int r    = rem / 14;
            int kk   = rem - r * 14;
            int grow = row0 + r;
            if (grow >= 0) {
                float4 v = *(const float4*)(xs + (size_t)c * HW_ + (size_t)grow * W_ + 4 * kk);
                float* d = &tb[(c * 3 + r) * TW + 4 * kk];   // 8B-aligned
                d[0] = v.x; d[1] = v.y; d[2] = v.z; d[3] = v.w;
            }
        }
    };

    const int g   = tid >> 5;                    // 8 groups of 32 lanes, 2 ch each
    const int wo  = tid & 31;
    const bool act = wo < WO_;

    float acc[9];
#pragma unroll
    for (int k = 0; k < 9; ++k) acc[k] = 0.f;

    // ---- phase 1: scores over all channels ----
    stage(bufA, 0);
    __syncthreads();
    for (int sub = 0; sub < NSUB; ++sub) {
        float* cur = (sub & 1) ? bufB : bufA;
        float* nxt = (sub & 1) ? bufA : bufB;
        if (sub + 1 < NSUB) stage(nxt, sub + 1);   // loads overlap compute below
        if (act) {
#pragma unroll
            for (int cc = 0; cc < 2; ++cc) {
                // window rows = tile rows 0..2; cols 2wo-1..2wo+1 (wo=0 col -1 -> pad zero)
                const float* tp = &cur[((g * 2 + cc) * 3) * TW + 2 * wo - 1];
                float w0 = tp[0],        w1 = tp[1],          w2 = tp[2];
                float w3 = tp[TW],       w4 = tp[TW + 1],     w5 = tp[TW + 2];
                float w6 = tp[2 * TW],   w7 = tp[2 * TW + 1], w8 = tp[2 * TW + 2];
                float q = ((w0 + w1) + (w2 + w3)) + ((w4 + w5) + (w6 + w7)) + w8;
                acc[0] += q * w0; acc[1] += q * w1; acc[2] += q * w2;
                acc[3] += q * w3; acc[4] += q * w4; acc[5] += q * w5;
                acc[6] += q * w6; acc[7] += q * w7; acc[8] += q * w8;
            }
        }
        __syncthreads();   // nxt staged AND cur reads done
    }

    // ---- reduce 8 groups + softmax, all in LDS ----
    if (act) {
#pragma unroll
        for (int k = 0; k < 9; ++k) sred[g * 252 + wo * 9 + k] = acc[k];
    }
    __syncthreads();
    stage(bufA, 0);                               // phase-2 prologue, overlaps softmax
    if (tid < 252) {
        float t = 0.f;
#pragma unroll
        for (int g2 = 0; g2 < 8; ++g2) t += sred[g2 * 252 + tid];
        attn_s[tid] = t * (1.f / 27.f);           // (1/9 q-mean) * (1/3 merge_kernel)
    }
    __syncthreads();
    if (tid < WO_) {
        float* s = &attn_s[tid * 9];
        float v[9];
#pragma unroll
        for (int k = 0; k < 9; ++k) v[k] = s[k];
        float m = v[0];
#pragma unroll
        for (int k = 1; k < 9; ++k) m = fmaxf(m, v[k]);
        float d = 0.f;
#pragma unroll
        for (int k = 0; k < 9; ++k) { v[k] = __expf(v[k] - m); d += v[k]; }
        float inv = 1.f / d;
#pragma unroll
        for (int k = 0; k < 9; ++k) s[k] = v[k] * inv;
    }
    __syncthreads();

    // ---- phase 2: merge, re-streaming the same sub-chunks (L3-hot) ----
    float* op = out + (size_t)n * C_ * (HO_ * WO_) + (size_t)ho * WO_;
    for (int sub = 0; sub < NSUB; ++sub) {
        float* cur = (sub & 1) ? bufB : bufA;
        float* nxt = (sub & 1) ? bufA : bufB;
        if (sub + 1 < NSUB) stage(nxt, sub + 1);
        for (int i = tid; i < SC * WO_; i += 256) {   // 448 outputs, 2 iters
            int c = i / WO_;
            int w = i - c * WO_;
            const float* a  = &attn_s[w * 9];
            const float* tp = &cur[(c * 3) * TW + 2 * w - 1];
            float y = a[0] * tp[0]        + a[1] * tp[1]          + a[2] * tp[2]
                    + a[3] * tp[TW]       + a[4] * tp[TW + 1]     + a[5] * tp[TW + 2]
                    + a[6] * tp[2 * TW]   + a[7] * tp[2 * TW + 1] + a[8] * tp[2 * TW + 2];
            op[(size_t)(sub * SC + c) * (HO_ * WO_) + w] = y;
        }
        __syncthreads();
    }
}

extern "C" void kernel_launch(void* const* d_in, const int* in_sizes, int n_in,
                              void* d_out, int out_size, void* d_ws, size_t ws_size,
                              hipStream_t stream) {
    const float* x = (const float*)d_in[0];
    float* out     = (float*)d_out;
    fused_kernel<<<dim3(N_ * HO_), dim3(256), 0, stream>>>(x, out);
}

// Round 5
// 566.043 us; speedup vs baseline: 1.0589x; 1.0589x over previous
//
#include <hip/hip_runtime.h>

// AttDownsample: x [32,768,56,56] f32 -> y [32,768,28,28] f32
// v5: fused, zero-ws (avoids harness 186us fill), ASYNC staging:
//  - linear TW=56 tile staged via __builtin_amdgcn_global_load_lds (width 16),
//    3 wave-instrs/stage, addresses precomputed per-thread; padding handled by
//    compute-side masks (ho==0 top row block-uniform, wo==0 left col per-lane).
//  - 2-deep pipeline, 3 LDS buffers, raw s_barrier + counted vmcnt(3) (never 0
//    in main loop; __syncthreads only in the one-shot softmax interlude).

constexpr int N_  = 32;
constexpr int C_  = 768;
constexpr int H_  = 56;
constexpr int W_  = 56;
constexpr int HO_ = 28;
constexpr int WO_ = 28;
constexpr int HW_ = H_ * W_;          // 3136

constexpr int SC      = 16;           // channels per stage
constexpr int NSUB    = C_ / SC;      // 48
constexpr int TILE_F4 = 768;          // 12 chunks x 64 float4 (672 data + dummy pad)
// stage = 672 float4 (16ch x 3rows x 14 f4), 11 chunks of 64; wave w loads
// chunks {w, w+4, w+8} (chunk 11 = dummy, clamped, written to pad slots).

#define WAITV3() do { asm volatile("s_waitcnt vmcnt(3)" ::: "memory"); \
                      __builtin_amdgcn_sched_barrier(0); } while (0)
#define WAITV0() do { asm volatile("s_waitcnt vmcnt(0)" ::: "memory"); \
                      __builtin_amdgcn_sched_barrier(0); } while (0)
#define RAWBAR() do { asm volatile("" ::: "memory"); __builtin_amdgcn_s_barrier(); \
                      __builtin_amdgcn_sched_barrier(0); } while (0)

__global__ __launch_bounds__(256)
void fused_kernel(const float* __restrict__ x, float* __restrict__ out) {
    __shared__ float4 bufs[3][TILE_F4];          // 36864 B
    __shared__ float  sred[8 * 252];             //  8064 B
    __shared__ float  attn_s[252];               //  1008 B

    const int tid  = threadIdx.x;
    const int blk  = blockIdx.x;
    const int n    = blk / HO_;
    const int ho   = blk - n * HO_;
    const int row0 = 2 * ho - 1;                 // input row of tile row 0
    const int lane = tid & 63;
    const int wv   = tid >> 6;

    // ---- precompute stage addressing (block/thread-invariant) ----
    int goff[3], lds4[3];
#pragma unroll
    for (int j = 0; j < 3; ++j) {
        int q  = wv + 4 * j;                     // chunk 0..11
        int i  = q * 64 + lane;                  // float4 item index
        int ii = i > 671 ? 671 : i;              // clamp dummy chunk
        int c  = ii / 42;
        int rem = ii - c * 42;
        int r  = rem / 14;
        int kk = rem - r * 14;
        int grow = row0 + r; if (grow < 0) grow = 0;   // ho==0 masked in compute
        goff[j] = c * HW_ + grow * W_ + 4 * kk;  // float offset within 16-ch slab
        lds4[j] = q * 64;                        // float4 slot (wave-uniform)
    }

    const float* xb = x + (size_t)n * C_ * HW_;
    auto stage = [&](int sub, int bsel) {
        const float* xs = xb + (size_t)sub * (SC * HW_);
        float4* tb = &bufs[bsel][0];
#pragma unroll
        for (int j = 0; j < 3; ++j)
            __builtin_amdgcn_global_load_lds(
                (const __attribute__((address_space(1))) unsigned int*)(xs + goff[j]),
                (__attribute__((address_space(3))) unsigned int*)(tb + lds4[j]),
                16, 0, 0);
    };

    // compute-role mapping
    const int g   = tid >> 5;                    // 8 groups x 2 channels
    const int wo  = tid & 31;
    const bool act = wo < WO_;
    const float mt  = (ho > 0) ? 1.f : 0.f;      // top-row mask (block-uniform)
    const float ml  = (wo > 0) ? 1.f : 0.f;      // left-col mask (per-lane)
    const float mtl = mt * ml;

    float acc[9];
#pragma unroll
    for (int k = 0; k < 9; ++k) acc[k] = 0.f;

    // ---- prologue: fill pipeline 2 deep ----
    stage(0, 0);
    stage(1, 1);
    WAITV3();                                    // drain stage 0 (stage 1 in flight)
    RAWBAR();

    // ---- phase 1: scores, t = 0..47 ----
    for (int t = 0; t < 48; ++t) {
        int s = t + 2;                           // stages 2..49 (48,49 wrap to sub 0,1)
        stage(s < 48 ? s : s - 48, s % 3);
        const float* cur = (const float*)&bufs[t % 3][0];
        if (act) {
#pragma unroll
            for (int cc = 0; cc < 2; ++cc) {
                const float* tp = cur + (g * 2 + cc) * 168 + 2 * wo - 1;
                float w0 = tp[0]   * mtl, w1 = tp[1]   * mt, w2 = tp[2]   * mt;
                float w3 = tp[56]  * ml,  w4 = tp[57],      w5 = tp[58];
                float w6 = tp[112] * ml,  w7 = tp[113],     w8 = tp[114];
                float q = ((w0 + w1) + (w2 + w3)) + ((w4 + w5) + (w6 + w7)) + w8;
                acc[0] += q * w0; acc[1] += q * w1; acc[2] += q * w2;
                acc[3] += q * w3; acc[4] += q * w4; acc[5] += q * w5;
                acc[6] += q * w6; acc[7] += q * w7; acc[8] += q * w8;
            }
        }
        WAITV3();                                // drain stage t+1, keep t+2 in flight
        RAWBAR();
    }

    // ---- softmax interlude (one-shot; __syncthreads drains vmcnt once, ok) ----
    if (act) {
#pragma unroll
        for (int k = 0; k < 9; ++k) sred[g * 252 + wo * 9 + k] = acc[k];
    }
    __syncthreads();
    if (tid < 252) {
        float t = 0.f;
#pragma unroll
        for (int g2 = 0; g2 < 8; ++g2) t += sred[g2 * 252 + tid];
        attn_s[tid] = t * (1.f / 27.f);          // (1/9 q-mean) * (1/3 merge_kernel)
    }
    __syncthreads();
    if (tid < WO_) {
        float* s = &attn_s[tid * 9];
        float v[9];
#pragma unroll
        for (int k = 0; k < 9; ++k) v[k] = s[k];
        float m = v[0];
#pragma unroll
        for (int k = 1; k < 9; ++k) m = fmaxf(m, v[k]);
        float d = 0.f;
#pragma unroll
        for (int k = 0; k < 9; ++k) { v[k] = __expf(v[k] - m); d += v[k]; }
        float inv = 1.f / d;
#pragma unroll
        for (int k = 0; k < 9; ++k) s[k] = v[k] * inv;
    }
    __syncthreads();

    // ---- phase 2: merge, t = 48..95 (re-stream, largely L3-hot) ----
    const int cA = tid / 28, wA = tid - cA * 28;             // item A: always active
    const int iB = tid + 256;
    const int cB = iB / 28, wB = iB - cB * 28;
    const bool actB = iB < 448;
    const float mlA = (wA > 0) ? 1.f : 0.f;
    const float mlB = (wB > 0) ? 1.f : 0.f;
    float* ob = out + (size_t)n * C_ * (HO_ * WO_) + (size_t)ho * WO_;

    for (int t = 48; t < 96; ++t) {
        if (t <= 93) stage(t + 2 - 48, (t + 2) % 3);
        const float* cur = (const float*)&bufs[t % 3][0];
        const int sub = t - 48;
        {
            const float* tp = cur + cA * 168 + 2 * wA - 1;
            const float* a  = &attn_s[wA * 9];
            float w0 = tp[0]   * (mt * mlA), w1 = tp[1]   * mt, w2 = tp[2] * mt;
            float w3 = tp[56]  * mlA,        w4 = tp[57],       w5 = tp[58];
            float w6 = tp[112] * mlA,        w7 = tp[113],      w8 = tp[114];
            float y = a[0]*w0 + a[1]*w1 + a[2]*w2 + a[3]*w3 + a[4]*w4
                    + a[5]*w5 + a[6]*w6 + a[7]*w7 + a[8]*w8;
            ob[(size_t)(sub * SC + cA) * (HO_ * WO_) + wA] = y;
        }
        if (actB) {
            const float* tp = cur + cB * 168 + 2 * wB - 1;
            const float* a  = &attn_s[wB * 9];
            float w0 = tp[0]   * (mt * mlB), w1 = tp[1]   * mt, w2 = tp[2] * mt;
            float w3 = tp[56]  * mlB,        w4 = tp[57],       w5 = tp[58];
            float w6 = tp[112] * mlB,        w7 = tp[113],      w8 = tp[114];
            float y = a[0]*w0 + a[1]*w1 + a[2]*w2 + a[3]*w3 + a[4]*w4
                    + a[5]*w5 + a[6]*w6 + a[7]*w7 + a[8]*w8;
            ob[(size_t)(sub * SC + cB) * (HO_ * WO_) + wB] = y;
        }
        if (t < 94) { WAITV3(); } else { WAITV0(); }
        RAWBAR();
    }
}

extern "C" void kernel_launch(void* const* d_in, const int* in_sizes, int n_in,
                              void* d_out, int out_size, void* d_ws, size_t ws_size,
                              hipStream_t stream) {
    const float* x = (const float*)d_in[0];
    float* out     = (float*)d_out;
    fused_kernel<<<dim3(N_ * HO_), dim3(256), 0, stream>>>(x, out);
}

// Round 6
// 521.181 us; speedup vs baseline: 1.1501x; 1.0861x over previous
//
#include <hip/hip_runtime.h>

// AttDownsample: x [32,768,56,56] f32 -> y [32,768,28,28] f32
// v6: fused, zero-ws, WAVE-PRIVATE async pipelines:
//  - each wave owns 4 channels/stage (its compute never touches the other 12),
//    staging 4ch x 3rows x 56 = 168 float4 into its own double-buffered LDS slab
//    via 3 global_load_lds instrs (64+64+40 lanes), per-wave vmcnt(3) pacing.
//  - NO barriers in the two streaming loops (waves drift freely; 24 waves/CU);
//    only 3 __syncthreads around the softmax. All 896 blocks resident (26.5 KB LDS).
//  - edge padding via compute-side masks (ho==0 top row, wo==0 left col).

constexpr int N_  = 32;
constexpr int C_  = 768;
constexpr int H_  = 56;
constexpr int W_  = 56;
constexpr int HO_ = 28;
constexpr int WO_ = 28;
constexpr int HW_ = H_ * W_;          // 3136

constexpr int SC   = 16;              // channels per stage (4 per wave)
constexpr int NSUB = C_ / SC;         // 48

#define WAITV3() do { asm volatile("s_waitcnt vmcnt(3)" ::: "memory"); \
                      __builtin_amdgcn_sched_barrier(0); } while (0)
#define WAITV0() do { asm volatile("s_waitcnt vmcnt(0)" ::: "memory"); \
                      __builtin_amdgcn_sched_barrier(0); } while (0)

__global__ __launch_bounds__(256)
void fused_kernel(const float* __restrict__ x, float* __restrict__ out) {
    __shared__ float4 bufs[4][2][168];           // [wave][dbuf][f4] = 21504 B
    __shared__ float  sred[4 * 252];             //  4032 B
    __shared__ float  attn_s[252];               //  1008 B  -> 26544 B total

    const int tid  = threadIdx.x;
    const int blk  = blockIdx.x;
    const int n    = blk / HO_;
    const int ho   = blk - n * HO_;
    const int row0 = 2 * ho - 1;                 // input row of window row 0
    const int lane = tid & 63;
    const int wv   = tid >> 6;

    // ---- per-thread stage addressing: item idx = j*64+lane in [0,168) ----
    int goff[3];
#pragma unroll
    for (int j = 0; j < 3; ++j) {
        int idx = j * 64 + lane;
        if (idx > 167) idx = 167;                // masked lanes: addr harmless
        int c   = idx / 42;                      // 0..3 (wave-local channel)
        int rem = idx - c * 42;
        int r   = rem / 14;
        int kk  = rem - r * 14;
        int grow = row0 + r; if (grow < 0) grow = 0;   // ho==0 masked in compute
        goff[j] = (4 * wv + c) * HW_ + grow * W_ + 4 * kk;
    }

    const float* xb = x + (size_t)n * C_ * HW_;
    auto stage = [&](int sub, int b) {
        const float* xs = xb + (size_t)sub * (SC * HW_);
        float4* tb = &bufs[wv][b][0];
        __builtin_amdgcn_global_load_lds(
            (const __attribute__((address_space(1))) unsigned int*)(xs + goff[0]),
            (__attribute__((address_space(3))) unsigned int*)(tb), 16, 0, 0);
        __builtin_amdgcn_global_load_lds(
            (const __attribute__((address_space(1))) unsigned int*)(xs + goff[1]),
            (__attribute__((address_space(3))) unsigned int*)(tb + 64), 16, 0, 0);
        if (lane < 40)
            __builtin_amdgcn_global_load_lds(
                (const __attribute__((address_space(1))) unsigned int*)(xs + goff[2]),
                (__attribute__((address_space(3))) unsigned int*)(tb + 128), 16, 0, 0);
    };

    // compute-role mapping: half-wave handles 2 of the wave's 4 channels
    const int half = lane >> 5;                  // 0/1
    const int wo   = lane & 31;                  // active < 28
    const float mt  = (ho > 0) ? 1.f : 0.f;      // top-row mask (block-uniform)
    const float ml  = (wo > 0) ? 1.f : 0.f;      // left-col mask (per-lane)
    const float mtl = mt * ml;

    float acc[9];
#pragma unroll
    for (int k = 0; k < 9; ++k) acc[k] = 0.f;

    // ---- phase 1: scores (per-wave pipeline, no barriers) ----
    stage(0, 0);
    for (int t = 0; t < NSUB; ++t) {
        if (t < NSUB - 1) { stage(t + 1, (t + 1) & 1); WAITV3(); }
        else              { WAITV0(); }
        const float* tbf = (const float*)&bufs[wv][t & 1][0];
#pragma unroll
        for (int cc = 0; cc < 2; ++cc) {
            const float* tp = tbf + (half * 2 + cc) * 168 + 2 * wo - 1;
            float w0 = tp[0]   * mtl, w1 = tp[1]   * mt, w2 = tp[2]   * mt;
            float w3 = tp[56]  * ml,  w4 = tp[57],      w5 = tp[58];
            float w6 = tp[112] * ml,  w7 = tp[113],     w8 = tp[114];
            float q = ((w0 + w1) + (w2 + w3)) + ((w4 + w5) + (w6 + w7)) + w8;
            acc[0] += q * w0; acc[1] += q * w1; acc[2] += q * w2;
            acc[3] += q * w3; acc[4] += q * w4; acc[5] += q * w5;
            acc[6] += q * w6; acc[7] += q * w7; acc[8] += q * w8;
        }
    }

    // prologue of phase 2 issued early: latency hides under softmax
    stage(0, 0);

    // ---- softmax interlude (the only barriers in the kernel) ----
#pragma unroll
    for (int k = 0; k < 9; ++k) acc[k] += __shfl_down(acc[k], 32);
    if (lane < WO_) {                            // lanes 0..27 hold ch-pair sums
#pragma unroll
        for (int k = 0; k < 9; ++k) sred[wv * 252 + lane * 9 + k] = acc[k];
    }
    __syncthreads();
    if (tid < 252) {
        float t = sred[tid] + sred[252 + tid] + sred[504 + tid] + sred[756 + tid];
        attn_s[tid] = t * (1.f / 27.f);          // (1/9 q-mean) * (1/3 merge_kernel)
    }
    __syncthreads();
    if (tid < WO_) {
        float* s = &attn_s[tid * 9];
        float v[9];
#pragma unroll
        for (int k = 0; k < 9; ++k) v[k] = s[k];
        float m = v[0];
#pragma unroll
        for (int k = 1; k < 9; ++k) m = fmaxf(m, v[k]);
        float d = 0.f;
#pragma unroll
        for (int k = 0; k < 9; ++k) { v[k] = __expf(v[k] - m); d += v[k]; }
        float inv = 1.f / d;
#pragma unroll
        for (int k = 0; k < 9; ++k) s[k] = v[k] * inv;
    }
    __syncthreads();                             // implicit vmcnt(0): buf0 landed

    // ---- phase 2: merge (per-wave pipeline, no barriers) ----
    float* ob = out + (size_t)n * C_ * (HO_ * WO_) + (size_t)ho * WO_;
    for (int t = 0; t < NSUB; ++t) {
        if (t < NSUB - 1) { stage(t + 1, (t + 1) & 1); WAITV3(); }
        else              { WAITV0(); }
        const float* tbf = (const float*)&bufs[wv][t & 1][0];
#pragma unroll
        for (int rep = 0; rep < 2; ++rep) {
            int item = rep * 64 + lane;          // 0..111 valid
            if (item < 112) {
                int c = item / 28, w = item - c * 28;
                float mlw = (w > 0) ? 1.f : 0.f;
                const float* tp = tbf + c * 168 + 2 * w - 1;
                const float* a  = &attn_s[w * 9];
                float w0 = tp[0]   * (mt * mlw), w1 = tp[1]   * mt, w2 = tp[2] * mt;
                float w3 = tp[56]  * mlw,        w4 = tp[57],       w5 = tp[58];
                float w6 = tp[112] * mlw,        w7 = tp[113],      w8 = tp[114];
                float y = a[0]*w0 + a[1]*w1 + a[2]*w2 + a[3]*w3 + a[4]*w4
                        + a[5]*w5 + a[6]*w6 + a[7]*w7 + a[8]*w8;
                ob[(size_t)(t * SC + 4 * wv + c) * (HO_ * WO_) + w] = y;
            }
        }
    }
}

extern "C" void kernel_launch(void* const* d_in, const int* in_sizes, int n_in,
                              void* d_out, int out_size, void* d_ws, size_t ws_size,
                              hipStream_t stream) {
    const float* x = (const float*)d_in[0];
    float* out     = (float*)d_out;
    fused_kernel<<<dim3(N_ * HO_), dim3(256), 0, stream>>>(x, out);
}